// Round 3
// baseline (182.207 us; speedup 1.0000x reference)
//
#include <hip/hip_runtime.h>
#include <cstdint>

#pragma clang fp contract(off)

#define BS   128
#define NQ   900
#define NC   91
#define NQC  (NQ * NC)   // 81900
#define Q4   (NQC / 4)   // 20475
#define HHALF 10238      // ceil(Q4/2)
#define THIRD (NQC / 3)  // 27300
#define T4   (THIRD / 4) // 6825
#define PRE  10000
#define POST 100
#define RUNSZ 4096
#define RUNS 3
#define KSTRIDE (RUNS * RUNSZ)    // 12288 keys per image
#define TBITS 13
#define TBINS (1 << TBITS)
#define TSHIFT (32 - TBITS)
#define K_WIN 16
#define M_CAP 11000

typedef unsigned long long ull;

// ---- workspace layout (bytes) ----
#define WS_GH     0                       // 256 * 8192 * 2B = 4 MB (per-image per-half hist)
#define WS_KEYS   (4 * 1024 * 1024)       // 128*12288*8 = 12.6 MB

__device__ __forceinline__ uint32_t fkey(float f) {
    uint32_t b = __float_as_uint(f);
    return (b & 0x80000000u) ? ~b : (b | 0x80000000u);
}
__device__ __forceinline__ uint32_t qclamp(uint32_t q) { return (q < NQ) ? q : (NQ - 1); }

// 64-bit shfl_xor via two 32-bit shuffles
__device__ __forceinline__ ull shflx(ull v, int j) {
    uint32_t lo = (uint32_t)__shfl_xor((int)(uint32_t)v, j, 64);
    uint32_t hi = (uint32_t)__shfl_xor((int)(uint32_t)(v >> 32), j, 64);
    return ((ull)hi << 32) | (ull)lo;
}
// cross-lane compare-exchange: element i on this lane, partner i^j on lane^j
__device__ __forceinline__ ull cex(ull v, int j, bool lower, bool desc) {
    ull pb = shflx(v, j);
    ull a = lower ? v : pb;
    ull b = lower ? pb : v;
    bool sw = desc ? (a < b) : (a > b);
    return sw ? pb : v;
}
// intra-lane compare-exchange: a at lower index, b at higher
__device__ __forceinline__ void ce(ull& a, ull& b, bool desc) {
    bool sw = desc ? (a < b) : (a > b);
    if (sw) { ull t = a; a = b; b = t; }
}

// ============ Kernel 1: per-image-half LDS histogram -> global (no scan here) ============
// 256 blocks (2/image) = full CU coverage. Plain uint16 stores (half-count <= 40950),
// no atomics into global, no zeroing needed.
__global__ void __launch_bounds__(1024) k_hist(const float* __restrict__ logits,
                                               uint16_t* __restrict__ ghist) {
    int img = blockIdx.x >> 1;
    int h = blockIdx.x & 1;
    const int tid = threadIdx.x;
    __shared__ uint32_t hist[TBINS];   // 32 KB
    for (int i = tid; i < TBINS; i += 1024) hist[i] = 0u;
    __syncthreads();
    const float4* lg4 = (const float4*)(logits + (size_t)img * NQC);
    const int lo = h * HHALF;
    const int hi = (lo + HHALF < Q4) ? (lo + HHALF) : Q4;
    for (int i = lo + tid; i < hi; i += 1024) {
        float4 v = lg4[i];
        atomicAdd(&hist[fkey(v.x) >> TSHIFT], 1u);
        atomicAdd(&hist[fkey(v.y) >> TSHIFT], 1u);
        atomicAdd(&hist[fkey(v.z) >> TSHIFT], 1u);
        atomicAdd(&hist[fkey(v.w) >> TSHIFT], 1u);
    }
    __syncthreads();
    uint16_t* g = ghist + (size_t)(img * 2 + h) * TBINS;
    for (int i = tid; i < TBINS; i += 1024) g[i] = (uint16_t)hist[i];
}

// ============ Kernel 2: Tlo scan + fused compact + register bitonic sort ============
// Prologue: sum the two half-histograms, run the suffix scan -> Tlo (3x redundant
// across runs, but parallel). Sort: each lane holds 4 chunk elements in registers
// (elem = chunk + e*64 + lane). All j<=128 steps are register/shfl ops (no LDS,
// no barriers, no bank conflicts); only the 10 cross-wave j>=256 steps touch LDS.
// Identical comparator network as before => bit-identical output.
__global__ void __launch_bounds__(1024, 8) k_sortcompact(const float* __restrict__ logits,
                                                         const uint16_t* __restrict__ ghist,
                                                         ull* __restrict__ keys) {
    int img = blockIdx.y;
    int run = blockIdx.x;
    const int tid = threadIdx.x;
    const int lane = tid & 63;
    const int wv = tid >> 6;
    __shared__ ull sh[RUNSZ];          // 32 KB
    __shared__ uint32_t hist[TBINS];   // 32 KB
    __shared__ uint32_t part[1024];
    __shared__ uint32_t part2[32];
    __shared__ uint32_t sTlo, sBlo, sCumAboveLo, sM;
    __shared__ uint32_t sCnt;
    if (tid == 0) sCnt = 0u;

    // ---- Tlo scan (moved from old k_select; identical arithmetic) ----
    {
        const uint16_t* g0 = ghist + (size_t)(img * 2) * TBINS;
        const uint16_t* g1 = g0 + TBINS;
        for (int i = tid; i < TBINS; i += 1024)
            hist[i] = (uint32_t)g0[i] + (uint32_t)g1[i];
        __syncthreads();
        {
            uint32_t s = 0;
            int base = tid * (TBINS / 1024);
            for (int j = 0; j < TBINS / 1024; ++j) s += hist[base + j];
            part[tid] = s;
        }
        __syncthreads();
        if (tid < 32) {
            uint32_t s2 = 0;
            for (int j = 0; j < 32; ++j) s2 += part[tid * 32 + j];
            part2[tid] = s2;
        }
        __syncthreads();
        if (tid == 0) {
            uint32_t cum = 0; int w = 31;
            for (; w > 0; --w) { if (cum + part2[w] >= PRE) break; cum += part2[w]; }
            int t = w * 32 + 31;
            for (; t > w * 32; --t) { if (cum + part[t] >= PRE) break; cum += part[t]; }
            int b = t * (TBINS / 1024) + (TBINS / 1024 - 1);
            for (; b > t * (TBINS / 1024); --b) { if (cum + hist[b] >= PRE) break; cum += hist[b]; }
            sBlo = (uint32_t)b;
            sCumAboveLo = cum;
            sM = cum + hist[b];
            sTlo = ((uint32_t)b) << TSHIFT;
        }
        __syncthreads();
        if (sM > M_CAP) {   // rare fallback: refine Tlo by 8 bits over FULL image
            uint32_t P = sBlo;
            for (int i = tid; i < 256; i += 1024) part[i] = 0u;
            __syncthreads();
            const float4* lg4img = (const float4*)(logits + (size_t)img * NQC);
            for (int i = tid; i < Q4; i += 1024) {
                float4 v = lg4img[i];
                uint32_t u;
                u = fkey(v.x); if ((u >> TSHIFT) == P) atomicAdd(&part[(u >> (TSHIFT - 8)) & 0xFFu], 1u);
                u = fkey(v.y); if ((u >> TSHIFT) == P) atomicAdd(&part[(u >> (TSHIFT - 8)) & 0xFFu], 1u);
                u = fkey(v.z); if ((u >> TSHIFT) == P) atomicAdd(&part[(u >> (TSHIFT - 8)) & 0xFFu], 1u);
                u = fkey(v.w); if ((u >> TSHIFT) == P) atomicAdd(&part[(u >> (TSHIFT - 8)) & 0xFFu], 1u);
            }
            __syncthreads();
            if (tid == 0) {
                uint32_t K = PRE - sCumAboveLo;
                uint32_t cum = 0; int x = 255;
                for (; x > 0; --x) { if (cum + part[x] >= K) break; cum += part[x]; }
                sTlo = (P << TSHIFT) | (((uint32_t)x) << (TSHIFT - 8));
            }
            __syncthreads();
        }
    }
    const uint32_t Tlo = sTlo;

    // ---- compaction (unchanged) ----
    const float4* lg4 = (const float4*)(logits + (size_t)img * NQC) + (size_t)run * T4;
    const int fbase = run * THIRD;
    for (int i0 = 0; i0 < T4; i0 += 1024) {
        int i = i0 + tid;
        bool inb = (i < T4);
        float4 v = inb ? lg4[i] : make_float4(0.f, 0.f, 0.f, 0.f);
        float comp[4] = {v.x, v.y, v.z, v.w};
        #pragma unroll
        for (int c = 0; c < 4; ++c) {
            uint32_t u = inb ? fkey(comp[c]) : 0u;
            bool pass = inb && (u >= Tlo);
            ull m = __ballot(pass);
            uint32_t below = (uint32_t)__popcll(m & ((1ull << lane) - 1ull));
            uint32_t wtot = (uint32_t)__popcll(m);
            uint32_t wb = 0u;
            if (lane == 0 && wtot) wb = atomicAdd(&sCnt, wtot);
            wb = __shfl(wb, 0, 64);
            if (pass) {
                uint32_t p = wb + below;
                uint32_t fi = (uint32_t)(fbase + i * 4 + c);
                if (p < RUNSZ) sh[p] = ((ull)u << 32) | (ull)(0xFFFFFFFFu - fi);
            }
        }
    }
    __syncthreads();
    uint32_t n = sCnt; if (n > RUNSZ) n = RUNSZ;
    for (int i = tid; i < RUNSZ; i += 1024) if (i >= (int)n) sh[i] = 0ull;
    __syncthreads();

    // ---- register bitonic: chunk = wave's 256 elems; r[e] = sh[cb + e*64 + lane] ----
    const int cb = wv << 8;
    ull r0 = sh[cb + lane], r1 = sh[cb + 64 + lane];
    ull r2 = sh[cb + 128 + lane], r3 = sh[cb + 192 + lane];

    // k = 2..32: dir per-lane from (lane & k); all steps cross-lane
    #pragma unroll
    for (int k2 = 2; k2 <= 32; k2 <<= 1) {
        bool d = ((lane & k2) == 0);
        #pragma unroll
        for (int j = 16; j >= 1; j >>= 1) {
            if (j <= (k2 >> 1)) {
                bool lw = ((lane & j) == 0);
                r0 = cex(r0, j, lw, d); r1 = cex(r1, j, lw, d);
                r2 = cex(r2, j, lw, d); r3 = cex(r3, j, lw, d);
            }
        }
    }
    // k = 64: dir per-register: (i & 64) = (e&1)<<6
    #pragma unroll
    for (int j = 32; j >= 1; j >>= 1) {
        bool lw = ((lane & j) == 0);
        r0 = cex(r0, j, lw, true);  r1 = cex(r1, j, lw, false);
        r2 = cex(r2, j, lw, true);  r3 = cex(r3, j, lw, false);
    }
    // k = 128: (i & 128) = ((e>>1)&1)<<7
    ce(r0, r1, true); ce(r2, r3, false);                  // j = 64 (intra-lane)
    #pragma unroll
    for (int j = 32; j >= 1; j >>= 1) {
        bool lw = ((lane & j) == 0);
        r0 = cex(r0, j, lw, true);  r1 = cex(r1, j, lw, true);
        r2 = cex(r2, j, lw, false); r3 = cex(r3, j, lw, false);
    }
    // k = 256: dir uniform per wave: (cb & 256)
    {
        bool d = ((wv & 1) == 0);
        ce(r0, r2, d); ce(r1, r3, d);                     // j = 128
        ce(r0, r1, d); ce(r2, r3, d);                     // j = 64
        #pragma unroll
        for (int j = 32; j >= 1; j >>= 1) {
            bool lw = ((lane & j) == 0);
            r0 = cex(r0, j, lw, d); r1 = cex(r1, j, lw, d);
            r2 = cex(r2, j, lw, d); r3 = cex(r3, j, lw, d);
        }
    }
    sh[cb + lane] = r0; sh[cb + 64 + lane] = r1;
    sh[cb + 128 + lane] = r2; sh[cb + 192 + lane] = r3;
    __syncthreads();

    // k = 512..4096: cross-wave j>=256 in LDS, then in-chunk tail in registers
    for (int k = 512; k <= RUNSZ; k <<= 1) {
        for (int j = k >> 1; j >= 256; j >>= 1) {
            for (int t = tid; t < RUNSZ / 2; t += 1024) {
                int i = ((t & ~(j - 1)) << 1) | (t & (j - 1));
                int ixj = i | j;
                ull a = sh[i], b = sh[ixj];
                bool sw = ((i & k) == 0) ? (a < b) : (a > b);
                if (sw) { sh[i] = b; sh[ixj] = a; }
            }
            __syncthreads();
        }
        bool d = ((cb & k) == 0);
        r0 = sh[cb + lane]; r1 = sh[cb + 64 + lane];
        r2 = sh[cb + 128 + lane]; r3 = sh[cb + 192 + lane];
        ce(r0, r2, d); ce(r1, r3, d);                     // j = 128
        ce(r0, r1, d); ce(r2, r3, d);                     // j = 64
        #pragma unroll
        for (int j = 32; j >= 1; j >>= 1) {
            bool lw = ((lane & j) == 0);
            r0 = cex(r0, j, lw, d); r1 = cex(r1, j, lw, d);
            r2 = cex(r2, j, lw, d); r3 = cex(r3, j, lw, d);
        }
        if (k < RUNSZ) {
            sh[cb + lane] = r0; sh[cb + 64 + lane] = r1;
            sh[cb + 128 + lane] = r2; sh[cb + 192 + lane] = r3;
            __syncthreads();
        }
    }
    // final chunk is in registers: store straight to global (coalesced 8B)
    ull* gbase = keys + (size_t)img * KSTRIDE + (size_t)run * RUNSZ;
    gbase[cb + lane] = r0; gbase[cb + 64 + lane] = r1;
    gbase[cb + 128 + lane] = r2; gbase[cb + 192 + lane] = r3;
}

// ============ Kernel 3: 3-way rank-merge + LAZY windowed greedy NMS (unchanged) ============
__global__ void __launch_bounds__(1024) k_nms(const ull* __restrict__ keys,
                                              const float* __restrict__ logits,
                                              const float* __restrict__ pred_boxes,
                                              const float* __restrict__ target_sizes,
                                              float* __restrict__ out) {
    int img = blockIdx.x;
    const int tid = threadIdx.x;
    const int lane = tid & 63;
    const int wv = tid >> 6;             // 16 waves
    __shared__ ull shA[KSTRIDE];         // 96 KB: 3 sorted runs
    __shared__ float4 shPB[NQ];          // 14.4 KB
    __shared__ uint32_t fidx[PRE];       // 40 KB: rank -> flat index
    __shared__ float aX1[POST], aY1[POST], aX2[POST], aY2[POST], aAr[POST];
    __shared__ int   aCl[POST];
    __shared__ float s_x1[K_WIN], s_y1[K_WIN], s_x2[K_WIN], s_y2[K_WIN];
    __shared__ int   s_cl[K_WIN];
    __shared__ uint32_t s_em[K_WIN];
    __shared__ uint32_t smx[16];
    __shared__ float sOffD;

    const float ih = target_sizes[img * 2 + 0];
    const float iw = target_sizes[img * 2 + 1];
    const float* pb = pred_boxes + (size_t)img * NQ * 4;
    const float* lg = logits + (size_t)img * NQC;
    const ull* kI = keys + (size_t)img * KSTRIDE;

    // ---- Phase 0: load 3 runs (keep reg copies) + pred_boxes ----
    ull xk[12];
    #pragma unroll
    for (int k = 0; k < 12; ++k) {
        xk[k] = kI[tid + k * 1024];
        shA[tid + k * 1024] = xk[k];
    }
    if (tid < NQ) shPB[tid] = ((const float4*)pb)[tid];
    __syncthreads();

    // ---- Phase 1: rank merge, breadth-first searches ----
    const int OB0[3] = {4096, 0, 0};      // other-run bases by own run id
    const int OB1[3] = {8192, 8192, 4096};
    uint32_t rnk[12];
    #pragma unroll
    for (int c4 = 0; c4 < 3; ++c4) {
        uint32_t p[8];
        #pragma unroll
        for (int j = 0; j < 8; ++j) p[j] = 0u;
        #pragma unroll
        for (int st = 0; st < 12; ++st) {
            const int s = 2048 >> st;
            ull v[8];
            #pragma unroll
            for (int j = 0; j < 8; ++j) {
                const int k = c4 * 4 + (j >> 1);
                const int ob = (j & 1) ? OB1[k >> 2] : OB0[k >> 2];
                v[j] = shA[ob + p[j] + s - 1];
            }
            #pragma unroll
            for (int j = 0; j < 8; ++j)
                if (v[j] > xk[c4 * 4 + (j >> 1)]) p[j] += (uint32_t)s;
        }
        #pragma unroll
        for (int j = 0; j < 8; ++j) {      // correction: count may be 4096
            const int k = c4 * 4 + (j >> 1);
            const int ob = (j & 1) ? OB1[k >> 2] : OB0[k >> 2];
            if (shA[ob + p[j]] > xk[k]) p[j] += 1u;
        }
        #pragma unroll
        for (int q2 = 0; q2 < 4; ++q2) {
            const int k = c4 * 4 + q2;
            rnk[k] = (uint32_t)((tid + k * 1024) & (RUNSZ - 1)) + p[2 * q2] + p[2 * q2 + 1];
        }
    }
    // scatter fidx + max-coord (over top-PRE only, matching reference)
    uint32_t lmx = 0u;
    #pragma unroll
    for (int k = 0; k < 12; ++k) {
        ull x = xk[k];
        if (x != 0ull && rnk[k] < PRE) {
            uint32_t fu = ~(uint32_t)x;
            fidx[rnk[k]] = fu;
            uint32_t q = qclamp(fu / NC);
            float4 bb = shPB[q];
            float x1 = (bb.x - 0.5f * bb.z) * iw;
            float y1 = (bb.y - 0.5f * bb.w) * ih;
            float x2 = (bb.x + 0.5f * bb.z) * iw;
            float y2 = (bb.y + 0.5f * bb.w) * ih;
            uint32_t km = fkey(fmaxf(fmaxf(x1, y1), fmaxf(x2, y2)));
            if (km > lmx) lmx = km;
        }
    }
    for (int off = 32; off > 0; off >>= 1) {
        uint32_t o = (uint32_t)__shfl_down((int)lmx, off, 64);
        if (o > lmx) lmx = o;
    }
    if (lane == 0) smx[wv] = lmx;
    __syncthreads();
    if (tid == 0) {
        uint32_t m = smx[0];
        for (int w2 = 1; w2 < 16; ++w2) if (smx[w2] > m) m = smx[w2];
        uint32_t b = (m & 0x80000000u) ? (m & 0x7FFFFFFFu) : ~m;
        sOffD = __uint_as_float(b) + 1.0f;   // max_coord + 1
    }
    __syncthreads();
    const float offD = sOffD;

    // ---- Phase 3: lazy windowed greedy. wave wv owns candidate rank base+wv ----
    int npick = 0;
    int base = 0;
    while (npick < POST) {
        if (base >= PRE) {   // active exhausted: reference repeats index 0
            uint32_t f0 = fidx[0];
            uint32_t q0 = qclamp(f0 / NC);
            uint32_t c0 = f0 - (f0 / NC) * NC;
            float4 bb = shPB[q0];
            float rx1 = (bb.x - 0.5f * bb.z) * iw;
            float ry1 = (bb.y - 0.5f * bb.w) * ih;
            float rx2 = (bb.x + 0.5f * bb.z) * iw;
            float ry2 = (bb.y + 0.5f * bb.w) * ih;
            float sc = 1.0f / (1.0f + expf(-lg[(f0 < NQC) ? f0 : 0]));
            for (int p2 = npick + tid; p2 < POST; p2 += 1024) {
                out[img * POST + p2] = sc;
                out[BS * POST + img * POST + p2] = (float)c0;
                float* ob2 = out + 2 * BS * POST + ((size_t)img * POST + p2) * 4;
                ob2[0] = rx1; ob2[1] = ry1; ob2[2] = rx2; ob2[3] = ry2;
            }
            break;
        }

        // stage A: each wave computes its candidate (wave-uniform), lane0 stages it
        const int r = base + wv;
        const bool val = (r < PRE);
        const uint32_t f = val ? fidx[r] : 0u;
        const float lgv = lg[(val && f < NQC) ? f : 0];    // issue early
        const uint32_t q = qclamp(f / NC);
        const uint32_t cc = f - (f / NC) * NC;
        float4 bb = shPB[q];
        const float x1 = (bb.x - 0.5f * bb.z) * iw;
        const float y1 = (bb.y - 0.5f * bb.w) * ih;
        const float x2 = (bb.x + 0.5f * bb.z) * iw;
        const float y2 = (bb.y + 0.5f * bb.w) * ih;
        if (lane == 0) {
            s_x1[wv] = x1; s_y1[wv] = y1; s_x2[wv] = x2; s_y2[wv] = y2;
            s_cl[wv] = val ? (int)cc : -1;
        }
        __syncthreads();

        // stage B: conflicts. offset arithmetic replicates reference (raw + o).
        const float o = (float)cc * offD;
        const float cx1 = x1 + o, cy1 = y1 + o, cx2 = x2 + o, cy2 = y2 + o;
        const float car = (cx2 - cx1) * (cy2 - cy1);
        bool cf = false;
        if (val && lane < wv && s_cl[lane] == (int)cc) {    // in-window, same class
            float jx1 = s_x1[lane] + o, jy1 = s_y1[lane] + o;
            float jx2 = s_x2[lane] + o, jy2 = s_y2[lane] + o;
            float arj = (jx2 - jx1) * (jy2 - jy1);
            float xx1 = fmaxf(jx1, cx1), yy1 = fmaxf(jy1, cy1);
            float xx2 = fminf(jx2, cx2), yy2 = fminf(jy2, cy2);
            float inter = fmaxf(xx2 - xx1, 0.0f) * fmaxf(yy2 - yy1, 0.0f);
            float uni = (arj + car) - inter;
            float iou = inter / fmaxf(uni, 1e-9f);
            cf = !(iou <= 0.7f);
        }
        uint32_t em = (uint32_t)(__ballot(cf) & 0xFFFFull);
        bool pf = false;
        for (int i2 = lane; i2 < npick; i2 += 64) {          // vs accepted picks
            if (aCl[i2] == (int)cc) {
                float jx1 = aX1[i2] + o, jy1 = aY1[i2] + o;
                float jx2 = aX2[i2] + o, jy2 = aY2[i2] + o;
                float arj = aAr[i2];
                float xx1 = fmaxf(jx1, cx1), yy1 = fmaxf(jy1, cy1);
                float xx2 = fminf(jx2, cx2), yy2 = fminf(jy2, cy2);
                float inter = fmaxf(xx2 - xx1, 0.0f) * fmaxf(yy2 - yy1, 0.0f);
                float uni = (arj + car) - inter;
                float iou = inter / fmaxf(uni, 1e-9f);
                pf |= !(iou <= 0.7f);
            }
        }
        bool anyPrior = (__ballot(pf) != 0ull);
        if (lane == 0)
            s_em[wv] = em | (anyPrior ? 0x80000000u : 0u) | (val ? 0u : 0x40000000u);
        __syncthreads();

        // stage C: uniform sequential resolution over the 16 window candidates
        uint32_t acc = 0u; int a = 0;
        const int room = POST - npick;
        #pragma unroll
        for (int w2 = 0; w2 < K_WIN; ++w2) {
            uint32_t ew = s_em[w2];
            if (!(ew & 0xC0000000u) && a < room && ((ew & 0xFFFFu & acc) == 0u)) {
                acc |= (1u << w2); ++a;
            }
        }

        // stage D: accepted waves write output + append to accepted list (parallel)
        if (((acc >> wv) & 1u) && lane == 0) {
            int p = npick + __popc(acc & ((1u << wv) - 1u));
            float sc = 1.0f / (1.0f + expf(-lgv));
            out[img * POST + p] = sc;
            out[BS * POST + img * POST + p] = (float)cc;
            float* ob2 = out + 2 * BS * POST + ((size_t)img * POST + p) * 4;
            ob2[0] = x1; ob2[1] = y1; ob2[2] = x2; ob2[3] = y2;
            aX1[p] = x1; aY1[p] = y1; aX2[p] = x2; aY2[p] = y2;
            aAr[p] = car; aCl[p] = (int)cc;
        }
        npick += a;
        base += K_WIN;
        // no end barrier needed: next iteration's stage-A barrier orders
        // stage-D accepted-list writes before stage-B reads.
    }
}

extern "C" void kernel_launch(void* const* d_in, const int* in_sizes, int n_in,
                              void* d_out, int out_size, void* d_ws, size_t ws_size,
                              hipStream_t stream) {
    const float* logits = (const float*)d_in[0];
    const float* boxes  = (const float*)d_in[1];
    const float* tsizes = (const float*)d_in[2];
    float* out = (float*)d_out;

    char* ws = (char*)d_ws;
    uint16_t* ghist = (uint16_t*)(ws + WS_GH);
    ull* keys = (ull*)(ws + WS_KEYS);

    k_hist<<<2 * BS, 1024, 0, stream>>>(logits, ghist);
    k_sortcompact<<<dim3(RUNS, BS), 1024, 0, stream>>>(logits, ghist, keys);
    k_nms<<<BS, 1024, 0, stream>>>(keys, logits, boxes, tsizes, out);
}